// Round 3
// 1169.235 us; speedup vs baseline: 1.2615x; 1.2615x over previous
//
#include <hip/hip_runtime.h>
#include <hip/hip_bf16.h>

typedef __bf16 bf16_t;
typedef __bf16 bf16x4 __attribute__((ext_vector_type(4)));
typedef __bf16 bf16x8 __attribute__((ext_vector_type(8)));
typedef float  f32x4  __attribute__((ext_vector_type(4)));

#define NUM_HEADS 32
#define HEAD_DIM 32
#define SEQ 49
#define SEQ2 (SEQ * SEQ)            /* 2401 */
#define DIM 1024
#define NWIN 64
#define BATCH 1024
#define MTOT (BATCH * SEQ)          /* 50176 = 392*128 */
#define SCALE 0.17677669529663687f  /* 32^-0.5 */

#define GLOBAL_AS __attribute__((address_space(1)))
#define LDS_AS    __attribute__((address_space(3)))

// async global->LDS, 16B per lane. lds base MUST be wave-uniform (goes to M0);
// HW writes base + lane*16. Source address is per-lane.
__device__ __forceinline__ void async_copy16(const bf16_t* g, bf16_t* l)
{
    __builtin_amdgcn_global_load_lds((const GLOBAL_AS uint32_t*)g,
                                     (LDS_AS uint32_t*)l, 16, 0, 0);
}

// ---------------------------------------------------------------------------
// fp32 -> bf16 convert (n % 4 == 0)
// ---------------------------------------------------------------------------
__global__ __launch_bounds__(256)
void f32_to_bf16(const float* __restrict__ in, bf16_t* __restrict__ out, int n)
{
    int i = (blockIdx.x * 256 + threadIdx.x) * 4;
    if (i < n) {
        float4 v = *(const float4*)(in + i);
        bf16x4 o = { (bf16_t)v.x, (bf16_t)v.y, (bf16_t)v.z, (bf16_t)v.w };
        *(bf16x4*)(out + i) = o;
    }
}

// ---------------------------------------------------------------------------
// out_w (c,o) fp32 -> wT (o,c) bf16
// ---------------------------------------------------------------------------
__global__ __launch_bounds__(256)
void transpose1024(const float* __restrict__ in, bf16_t* __restrict__ out)
{
    __shared__ float tile[32][33];
    const int bx = blockIdx.x, by = blockIdx.y;
    const int tx = threadIdx.x & 31, ty = threadIdx.x >> 5;
    for (int r = ty; r < 32; r += 8)
        tile[r][tx] = in[(size_t)(by * 32 + r) * 1024 + bx * 32 + tx];
    __syncthreads();
    for (int r = ty; r < 32; r += 8)
        out[(size_t)(bx * 32 + r) * 1024 + by * 32 + tx] = (bf16_t)tile[tx][r];
}

// ---------------------------------------------------------------------------
// TRANSPOSED bias gather: biasT[h][j*SEQ + i] = rp_table[rp_index[i*SEQ+j]*32 + h]
// (attn reads i = lane-consecutive -> coalesced)
// ---------------------------------------------------------------------------
__global__ __launch_bounds__(256)
void bias_gather_t(const float* __restrict__ rp_table, const int* __restrict__ rp_index,
                   float* __restrict__ biasT)
{
    int idx = blockIdx.x * 256 + threadIdx.x;
    if (idx < NUM_HEADS * SEQ2) {
        int h   = idx / SEQ2;
        int rem = idx - h * SEQ2;          // rem = j*SEQ + i
        int j = rem / SEQ, i = rem - j * SEQ;
        biasT[idx] = rp_table[rp_index[i * SEQ + j] * NUM_HEADS + h];
    }
}

// maskT[w][j*SEQ + i] = mask[w][i*SEQ + j]
__global__ __launch_bounds__(256)
void mask_transpose(const float* __restrict__ mask, float* __restrict__ maskT)
{
    int idx = blockIdx.x * 256 + threadIdx.x;
    if (idx < NWIN * SEQ2) {
        int wd  = idx / SEQ2;
        int rem = idx - wd * SEQ2;         // j*SEQ + i
        int j = rem / SEQ, i = rem - j * SEQ;
        maskT[idx] = mask[wd * SEQ2 + i * SEQ + j];
    }
}

// ---------------------------------------------------------------------------
// bt-GEMM, m97 structure (unchanged, proven): C[m][n] = sum_k A[m][k]*W[n][k] + bias[n]
// ---------------------------------------------------------------------------
template<typename TC>
__global__ __launch_bounds__(256)
void gemm_bt(const bf16_t* __restrict__ A, int lda,
             const bf16_t* __restrict__ W,
             const float* __restrict__ bias,
             TC* __restrict__ C, int N, int K)
{
    __shared__ __align__(16) bf16_t As[128][32];
    __shared__ __align__(16) bf16_t Ws[128][32];

    const int tid  = threadIdx.x;
    const int lane = tid & 63;
    const int wave = tid >> 6;
    const int wm = wave >> 1, wn = wave & 1;
    const int l15 = lane & 15, lqq = lane >> 4;
    const int m0 = blockIdx.y * 128;
    const int n0 = blockIdx.x * 128;

    f32x4 acc[4][4] = {};

    for (int k0 = 0; k0 < K; k0 += 32) {
        #pragma unroll
        for (int it = 0; it < 2; ++it) {
            int c   = it * 256 + wave * 64 + lane;
            int row = c >> 2;
            int col = (c & 3) << 3;
            bf16_t* lbA = &As[0][0] + (size_t)(it * 256 + wave * 64) * 8;
            bf16_t* lbW = &Ws[0][0] + (size_t)(it * 256 + wave * 64) * 8;
            async_copy16(A + (size_t)(m0 + row) * lda + k0 + col, lbA);
            async_copy16(W + (size_t)(n0 + row) * K   + k0 + col, lbW);
        }
        __syncthreads();

        bf16x8 af[4], wf[4];
        #pragma unroll
        for (int i = 0; i < 4; ++i)
            af[i] = *(const bf16x8*)(&As[wm * 64 + i * 16 + l15][lqq * 8]);
        #pragma unroll
        for (int j = 0; j < 4; ++j)
            wf[j] = *(const bf16x8*)(&Ws[wn * 64 + j * 16 + l15][lqq * 8]);

        #pragma unroll
        for (int i = 0; i < 4; ++i)
            #pragma unroll
            for (int j = 0; j < 4; ++j)
                acc[i][j] = __builtin_amdgcn_mfma_f32_16x16x32_bf16(
                    af[i], wf[j], acc[i][j], 0, 0, 0);
        __syncthreads();
    }

    #pragma unroll
    for (int i = 0; i < 4; ++i) {
        #pragma unroll
        for (int j = 0; j < 4; ++j) {
            int col = n0 + wn * 64 + j * 16 + l15;
            float bv = bias[col];
            #pragma unroll
            for (int r = 0; r < 4; ++r) {
                int row = m0 + wm * 64 + i * 16 + lqq * 4 + r;
                C[(size_t)row * N + col] = (TC)(acc[i][j][r] + bv);
            }
        }
    }
}

// ---------------------------------------------------------------------------
// MFMA attention v3 (de-risked): one block (4 waves) per (b,h), wave wv owns
// q-rows [16wv,16wv+16).
//   NEW (kept from v2): swapped QK^T -- sacc[jt] = mfma(K,Q) puts
//   S[i=wv*16+l15][j=jt*16+lq*4+r] in registers; softmax is 15 in-lane fmax
//   + 2 shfl_xor + 16 exp, all 256 lanes busy, no LDS score buffer.
//   REVERTED to round-0-proven data movement: plain uint4 staging into
//   padded qs/ks[64][40]; scalar-transpose V into vt[32][72]; P via padded
//   Ps[64][72] with a __syncthreads(); plain bf16x8 fragment reads.
// Rows 49..63 stage in-bounds garbage (next window / wT region, finite bf16):
// j-pads forced to -1e30 -> P=0 exactly (0*garbage=0 in MFMA); i-pads never
// stored. LDS 23.5KB -> 6 blocks/CU (was 41.4KB -> 3). 2 barriers (was 4).
// ---------------------------------------------------------------------------
__global__ __launch_bounds__(256, 4)
void attn_mfma(bf16_t* __restrict__ qkv, const float* __restrict__ maskT,
               const float* __restrict__ biasT)
{
    __shared__ __align__(16) bf16_t qs[64][40];   // stride 40: conflict-light
    __shared__ __align__(16) bf16_t ks[64][40];
    __shared__ __align__(16) bf16_t vt[32][72];   // V^T: [d][j]
    __shared__ __align__(16) bf16_t Ps[64][72];   // P: [i][j]

    const int tid  = threadIdx.x;
    const int lane = tid & 63;
    const int wv   = tid >> 6;
    const int l15  = lane & 15, lq = lane >> 4;
    const int b  = blockIdx.x >> 5;
    const int h  = blockIdx.x & 31;
    const int wd = b & (NWIN - 1);
    const size_t base = (size_t)b * (SEQ * 3 * DIM) + h * HEAD_DIM;

    // ---- stage q,k,v: one 16B chunk per thread per tensor (all 64 rows) ----
    {
        const int n  = tid >> 2;                  // row 0..63
        const int c8 = (tid & 3) << 3;            // col 0,8,16,24
        const bf16_t* g = qkv + base + (size_t)n * (3 * DIM);
        *(uint4*)(&qs[n][c8]) = *(const uint4*)(g + c8);
        *(uint4*)(&ks[n][c8]) = *(const uint4*)(g + DIM + c8);
        uint4 v = *(const uint4*)(g + 2 * DIM + c8);
        const bf16_t* pv = (const bf16_t*)&v;
        #pragma unroll
        for (int j = 0; j < 8; ++j) vt[c8 + j][n] = pv[j];
    }
    __syncthreads();

    // ---- S^T = mfma(K, Q): lane holds S[i = wv*16+l15][j = jt*16+lq*4+r] ----
    const f32x4 zero4 = {0.f, 0.f, 0.f, 0.f};
    const int iq = wv * 16 + l15;
    bf16x8 qf = *(const bf16x8*)(&qs[iq][lq * 8]);
    f32x4 sacc[4];
    #pragma unroll
    for (int jt = 0; jt < 4; ++jt) {
        bf16x8 kf = *(const bf16x8*)(&ks[jt * 16 + l15][lq * 8]);
        sacc[jt] = __builtin_amdgcn_mfma_f32_16x16x32_bf16(kf, qf, zero4, 0, 0, 0);
    }

    // ---- scale + bias + mask (transposed tables: [.., j*SEQ + i]) ----
    const bool iv = iq < SEQ;
    const float* bT = biasT + (size_t)h  * SEQ2 + iq;
    const float* mT = maskT + (size_t)wd * SEQ2 + iq;
    float p[16];
    #pragma unroll
    for (int jt = 0; jt < 4; ++jt)
        #pragma unroll
        for (int r = 0; r < 4; ++r) {
            int j = jt * 16 + lq * 4 + r;
            float v = -1e30f;
            if (iv && j < SEQ)
                v = sacc[jt][r] * SCALE + bT[j * SEQ] + mT[j * SEQ];
            p[jt * 4 + r] = v;
        }

    // ---- wave-parallel softmax over j: 15 in-lane fmax + lanes {^16,^32} ----
    float m = p[0];
    #pragma unroll
    for (int t = 1; t < 16; ++t) m = fmaxf(m, p[t]);
    m = fmaxf(m, __shfl_xor(m, 16));
    m = fmaxf(m, __shfl_xor(m, 32));
    float sum = 0.f;
    #pragma unroll
    for (int t = 0; t < 16; ++t) { p[t] = __expf(p[t] - m); sum += p[t]; }
    sum += __shfl_xor(sum, 16);
    sum += __shfl_xor(sum, 32);
    const float inv = 1.f / sum;

    // ---- P -> bf16 quads into Ps[i][j] ----
    #pragma unroll
    for (int jt = 0; jt < 4; ++jt) {
        bf16x4 q4 = { (bf16_t)(p[jt * 4 + 0] * inv), (bf16_t)(p[jt * 4 + 1] * inv),
                      (bf16_t)(p[jt * 4 + 2] * inv), (bf16_t)(p[jt * 4 + 3] * inv) };
        *(bf16x4*)(&Ps[iq][jt * 16 + lq * 4]) = q4;
    }
    __syncthreads();

    // ---- O = P @ V (round-0-proven fragment reads) ----
    bf16x8 pf0 = *(const bf16x8*)(&Ps[iq][lq * 8]);
    bf16x8 pf1 = *(const bf16x8*)(&Ps[iq][32 + lq * 8]);
    #pragma unroll
    for (int dt = 0; dt < 2; ++dt) {
        bf16x8 vf0 = *(const bf16x8*)(&vt[dt * 16 + l15][lq * 8]);
        bf16x8 vf1 = *(const bf16x8*)(&vt[dt * 16 + l15][32 + lq * 8]);
        f32x4 o = __builtin_amdgcn_mfma_f32_16x16x32_bf16(pf0, vf0, zero4, 0, 0, 0);
        o = __builtin_amdgcn_mfma_f32_16x16x32_bf16(pf1, vf1, o, 0, 0, 0);
        #pragma unroll
        for (int r = 0; r < 4; ++r) {
            int i = wv * 16 + lq * 4 + r;
            if (i < SEQ)
                qkv[base + (size_t)i * (3 * DIM) + dt * 16 + l15] = (bf16_t)o[r];
        }
    }
}

// ---------------------------------------------------------------------------
extern "C" void kernel_launch(void* const* d_in, const int* in_sizes, int n_in,
                              void* d_out, int out_size, void* d_ws, size_t ws_size,
                              hipStream_t stream)
{
    const float* x        = (const float*)d_in[0];  // (1024,49,1024)
    const float* mask     = (const float*)d_in[1];  // (64,49,49)
    const float* qkv_w    = (const float*)d_in[3];  // (3072,1024) = (N,K)
    const float* qkv_b    = (const float*)d_in[4];  // (3072,)
    const float* rp_table = (const float*)d_in[5];  // (169,32)
    const float* out_w    = (const float*)d_in[6];  // (1024,1024) = (K,N)
    const float* out_b    = (const float*)d_in[7];  // (1024,)
    const int*   rp_index = (const int*)d_in[8];    // (49,49)
    float* out = (float*)d_out;                     // (1024,49,1024) fp32

    // ws: [ qkv bf16 50176x3072 | wT bf16 1024x1024 ]
    bf16_t* qkv = (bf16_t*)d_ws;
    bf16_t* wT  = (bf16_t*)((char*)d_ws + (size_t)MTOT * 3072 * sizeof(bf16_t));

    // d_out doubles as scratch until GEMM2 overwrites it (stream-ordered):
    // [ xb bf16 50176x1024 | wb bf16 3072x1024 | biasT fp32 32x2401 | maskT fp32 64x2401 ]
    bf16_t* xb    = (bf16_t*)d_out;
    bf16_t* wb    = (bf16_t*)((char*)d_out + (size_t)MTOT * DIM * sizeof(bf16_t));
    float*  biasT = (float*)((char*)d_out + (size_t)MTOT * DIM * sizeof(bf16_t)
                                          + (size_t)3 * DIM * DIM * sizeof(bf16_t));
    float*  maskT = biasT + (size_t)NUM_HEADS * SEQ2;

    // prepasses
    f32_to_bf16<<<(MTOT * DIM / 4 + 255) / 256, 256, 0, stream>>>(x, xb, MTOT * DIM);
    f32_to_bf16<<<(3 * DIM * DIM / 4 + 255) / 256, 256, 0, stream>>>(qkv_w, wb, 3 * DIM * DIM);
    transpose1024<<<dim3(32, 32), 256, 0, stream>>>(out_w, wT);
    bias_gather_t<<<(NUM_HEADS * SEQ2 + 255) / 256, 256, 0, stream>>>(rp_table, rp_index, biasT);
    mask_transpose<<<(NWIN * SEQ2 + 255) / 256, 256, 0, stream>>>(mask, maskT);

    // QKV projection: (50176,1024) @ (3072,1024)^T -> (50176,3072) bf16
    gemm_bt<bf16_t><<<dim3(3072 / 128, MTOT / 128), 256, 0, stream>>>(
        xb, DIM, wb, qkv_b, qkv, 3072, DIM);

    // attention per (b,h), in-place into q-slice
    attn_mfma<<<dim3(BATCH * NUM_HEADS), 256, 0, stream>>>(qkv, maskT, biasT);

    // output projection: (50176,1024 @ lda 3072) @ wT^T -> fp32 d_out
    gemm_bt<float><<<dim3(1024 / 128, MTOT / 128), 256, 0, stream>>>(
        qkv, 3072, wT, out_b, out, DIM, DIM);
}